// Round 1
// baseline (372.180 us; speedup 1.0000x reference)
//
#include <hip/hip_runtime.h>
#include <math.h>

// Problem constants (from reference): B=4096, D=256, N=2B=8192
#define D_DIM 256
#define UNIFORM_T 2.0f

// ---------------------------------------------------------------------------
// Block-wide all-reduce sum for 256-thread blocks (4 waves of 64).
// Returns the full sum broadcast to all threads.
__device__ __forceinline__ float blockAllReduceSum(float v, float* smem4) {
    #pragma unroll
    for (int off = 32; off > 0; off >>= 1) v += __shfl_down(v, off, 64);
    int lane = threadIdx.x & 63;
    int wid  = threadIdx.x >> 6;
    if (lane == 0) smem4[wid] = v;
    __syncthreads();
    float r = smem4[0] + smem4[1] + smem4[2] + smem4[3];
    __syncthreads();  // safe smem reuse
    return r;
}

// ---------------------------------------------------------------------------
// Kernel A: per-row L2 normalize a and b, write concatenated X=[a_n; b_n],
// write per-row squared norms SQ, accumulate alignment sum ||a_i - b_i||^2.
// One 256-thread block per row-pair i (D=256 -> one element per thread).
__global__ __launch_bounds__(256) void normalize_align_kernel(
        const float* __restrict__ A, const float* __restrict__ Bm,
        float* __restrict__ X, float* __restrict__ SQ,
        float* __restrict__ accums, int B_rows) {
    __shared__ float smem4[4];
    int i = blockIdx.x;
    int t = threadIdx.x;

    float av = A[i * D_DIM + t];
    float bv = Bm[i * D_DIM + t];

    float sa = blockAllReduceSum(av * av, smem4);
    float sb = blockAllReduceSum(bv * bv, smem4);

    float denA = fmaxf(sqrtf(sa), 1e-12f);
    float denB = fmaxf(sqrtf(sb), 1e-12f);

    float an = av / denA;
    float bn = bv / denB;

    X[i * D_DIM + t]            = an;
    X[(B_rows + i) * D_DIM + t] = bn;

    float d = an - bn;
    float sd = blockAllReduceSum(d * d, smem4);

    if (t == 0) {
        SQ[i]          = sa / (denA * denA);
        SQ[B_rows + i] = sb / (denB * denB);
        atomicAdd(&accums[0], sd);
    }
}

// ---------------------------------------------------------------------------
// Kernel B: uniformity pair sum. Tiled "Gram" over X (n x 256):
//   for each pair (i,j): e += exp(-t * max(sq_i + sq_j - 2*dot(x_i,x_j), 0))
// 64x64 tile per block, 16x16 threads, 4x4 outputs per thread, BK=16.
// Symmetry: only jb >= ib computed; off-diagonal blocks weighted 2x.
#define BI 64
#define BJ 64
#define BK 16
#define LDSW 68   // padded row stride (floats): 16B-aligned rows, 2-way-max banks

__global__ __launch_bounds__(256) void uniform_kernel(
        const float* __restrict__ X, const float* __restrict__ SQ,
        float* __restrict__ accums) {
    int ib = blockIdx.x;
    int jb = blockIdx.y;
    if (jb < ib) return;  // symmetric: skip lower triangle of block grid
    float scale = (jb == ib) ? 1.0f : 2.0f;

    __shared__ float As[BK * LDSW];
    __shared__ float Bs[BK * LDSW];
    __shared__ float sqa[BI];
    __shared__ float sqb[BJ];

    int t  = threadIdx.x;
    int tx = t & 15;   // j sub-tile
    int ty = t >> 4;   // i sub-tile

    if (t < BI)            sqa[t]      = SQ[ib * BI + t];
    else if (t < BI + BJ)  sqb[t - BI] = SQ[jb * BJ + (t - BI)];

    const float* Abase = X + (size_t)(ib * BI) * D_DIM;
    const float* Bbase = X + (size_t)(jb * BJ) * D_DIM;

    float acc[4][4] = {};

    for (int k0 = 0; k0 < D_DIM; k0 += BK) {
        __syncthreads();  // guard LDS reuse (also covers sqa/sqb first iter)
        #pragma unroll
        for (int r = 0; r < 4; ++r) {
            int l   = t + 256 * r;
            int row = l >> 4;   // 0..63
            int col = l & 15;   // 0..15
            As[col * LDSW + row] = Abase[row * D_DIM + k0 + col];
            Bs[col * LDSW + row] = Bbase[row * D_DIM + k0 + col];
        }
        __syncthreads();
        #pragma unroll
        for (int k = 0; k < BK; ++k) {
            float4 a4 = *reinterpret_cast<const float4*>(&As[k * LDSW + ty * 4]);
            float4 b4 = *reinterpret_cast<const float4*>(&Bs[k * LDSW + tx * 4]);
            float a[4] = {a4.x, a4.y, a4.z, a4.w};
            float b[4] = {b4.x, b4.y, b4.z, b4.w};
            #pragma unroll
            for (int u = 0; u < 4; ++u)
                #pragma unroll
                for (int v = 0; v < 4; ++v)
                    acc[u][v] = fmaf(a[u], b[v], acc[u][v]);
        }
    }

    // epilogue: exp(-t*d2) and reduce
    float s = 0.0f;
    #pragma unroll
    for (int u = 0; u < 4; ++u) {
        float si = sqa[ty * 4 + u];
        #pragma unroll
        for (int v = 0; v < 4; ++v) {
            float d2 = fmaxf(si + sqb[tx * 4 + v] - 2.0f * acc[u][v], 0.0f);
            s += __expf(-UNIFORM_T * d2);
        }
    }
    s *= scale;

    #pragma unroll
    for (int off = 32; off > 0; off >>= 1) s += __shfl_down(s, off, 64);
    __shared__ float red[4];
    if ((t & 63) == 0) red[t >> 6] = s;
    __syncthreads();
    if (t == 0) atomicAdd(&accums[1], red[0] + red[1] + red[2] + red[3]);
}

// ---------------------------------------------------------------------------
__global__ void finalize_kernel(const float* __restrict__ accums,
                                float* __restrict__ out, int B_rows) {
    float n = (float)(2 * B_rows);
    float align_loss   = accums[0] / (float)B_rows;
    float uniform_loss = (accums[1] - n) / (n * (n - 1.0f));
    out[0] = align_loss + uniform_loss;
}

// ---------------------------------------------------------------------------
extern "C" void kernel_launch(void* const* d_in, const int* in_sizes, int n_in,
                              void* d_out, int out_size, void* d_ws, size_t ws_size,
                              hipStream_t stream) {
    const float* A  = (const float*)d_in[0];
    const float* Bm = (const float*)d_in[1];
    float* out = (float*)d_out;

    int B_rows = in_sizes[0] / D_DIM;   // 4096
    int n_tot  = 2 * B_rows;            // 8192

    // Workspace layout: X (n_tot*256 f32) | SQ (n_tot f32) | accums (2 f32)
    float* X      = (float*)d_ws;
    float* SQ     = X + (size_t)n_tot * D_DIM;
    float* accums = SQ + n_tot;

    hipMemsetAsync(accums, 0, 2 * sizeof(float), stream);

    normalize_align_kernel<<<B_rows, 256, 0, stream>>>(A, Bm, X, SQ, accums, B_rows);

    int nb = n_tot / BI;  // 128
    uniform_kernel<<<dim3(nb, nb), 256, 0, stream>>>(X, SQ, accums);

    finalize_kernel<<<1, 1, 0, stream>>>(accums, out, B_rows);
}

// Round 2
// 98.378 us; speedup vs baseline: 3.7832x; 3.7832x over previous
//
#include <hip/hip_runtime.h>
#include <math.h>

#define D_DIM 256

typedef __attribute__((ext_vector_type(8))) short short8v;
typedef __attribute__((ext_vector_type(16))) float f32x16;

#define AS_GLOBAL(p) ((const __attribute__((address_space(1))) void*)(p))
#define AS_LDS(p)    ((__attribute__((address_space(3))) void*)(p))

// RNE float -> bf16 (finite inputs)
__device__ __forceinline__ unsigned short f2bf(float f) {
    unsigned int u = __float_as_uint(f);
    unsigned int r = (u + 0x7fffu + ((u >> 16) & 1u)) >> 16;
    return (unsigned short)r;
}

// ---------------------------------------------------------------------------
// Kernel A: per-wave row normalize. Block=256 (4 waves), wave w handles row
// i = blockIdx.x*4+w. Lane holds 4 elems (float4). Shuffle-only reductions.
// Writes bf16 X=[a_n;b_n], f32 SQ, and per-block align partial (hashed slots).
__global__ __launch_bounds__(256) void normalize_kernel(
        const float* __restrict__ A, const float* __restrict__ Bm,
        unsigned short* __restrict__ Xb, float* __restrict__ SQ,
        float* __restrict__ partials, int B_rows) {
    __shared__ float red[4];
    int lane = threadIdx.x & 63;
    int w    = threadIdx.x >> 6;
    int i    = blockIdx.x * 4 + w;

    const float4* A4 = (const float4*)(A + (size_t)i * D_DIM);
    const float4* B4 = (const float4*)(Bm + (size_t)i * D_DIM);
    float4 av = A4[lane];
    float4 bv = B4[lane];

    float sa = av.x*av.x + av.y*av.y + av.z*av.z + av.w*av.w;
    float sb = bv.x*bv.x + bv.y*bv.y + bv.z*bv.z + bv.w*bv.w;
    #pragma unroll
    for (int off = 32; off > 0; off >>= 1) {
        sa += __shfl_xor(sa, off, 64);
        sb += __shfl_xor(sb, off, 64);
    }
    float dena = fmaxf(sqrtf(sa), 1e-12f);
    float denb = fmaxf(sqrtf(sb), 1e-12f);
    float ia = 1.0f / dena, ib = 1.0f / denb;

    float4 an = {av.x*ia, av.y*ia, av.z*ia, av.w*ia};
    float4 bn = {bv.x*ib, bv.y*ib, bv.z*ib, bv.w*ib};

    ushort4 ua = {f2bf(an.x), f2bf(an.y), f2bf(an.z), f2bf(an.w)};
    ushort4 ub = {f2bf(bn.x), f2bf(bn.y), f2bf(bn.z), f2bf(bn.w)};
    ((ushort4*)(Xb + (size_t)i * D_DIM))[lane]            = ua;
    ((ushort4*)(Xb + (size_t)(B_rows + i) * D_DIM))[lane] = ub;

    float dx = an.x-bn.x, dy = an.y-bn.y, dz = an.z-bn.z, dw = an.w-bn.w;
    float sd = dx*dx + dy*dy + dz*dz + dw*dw;
    #pragma unroll
    for (int off = 32; off > 0; off >>= 1) sd += __shfl_down(sd, off, 64);

    if (lane == 0) {
        SQ[i]          = sa * ia * ia;
        SQ[B_rows + i] = sb * ib * ib;
        red[w] = sd;
    }
    __syncthreads();
    if (threadIdx.x == 0)
        atomicAdd(&partials[blockIdx.x & 63], red[0]+red[1]+red[2]+red[3]);
}

// ---------------------------------------------------------------------------
// Kernel B: uniformity via bf16 MFMA Gram. 128x128 tile, 4 waves (2x2 of
// 64x64/wave), BK=64 LDS staging via global_load_lds(16B) with both-sides
// XOR swizzle (linear LDS dest, inverse-swizzled global source, swizzled
// ds_read_b128). Upper-triangle blocks only; off-diagonal weighted 2x.
__device__ __forceinline__ short8v frag_read(const unsigned short* base, int r, int kb) {
    int off = r * 128 + (kb ^ ((r & 7) << 4));
    return *reinterpret_cast<const short8v*>(reinterpret_cast<const char*>(base) + off);
}

__global__ __launch_bounds__(256) void uniform_mfma_kernel(
        const unsigned short* __restrict__ Xb, const float* __restrict__ SQ,
        float* __restrict__ partials) {
    int ib = blockIdx.x, jb = blockIdx.y;
    if (jb < ib) return;

    __shared__ __align__(16) unsigned short As[128 * 64];  // 16 KB, [row][k] swizzled
    __shared__ __align__(16) unsigned short Bs[128 * 64];
    __shared__ float sqa[128], sqb[128], red[4];

    int t    = threadIdx.x;
    int lane = t & 63;
    int w    = t >> 6;
    int wr   = w >> 1, wc = w & 1;

    int rowA0 = ib * 128, rowB0 = jb * 128;
    if (t < 128) sqa[t] = SQ[rowA0 + t];
    else         sqb[t - 128] = SQ[rowB0 + t - 128];

    f32x16 acc[2][2] = {};

    int r_a0 = wr * 64 + (lane & 31), r_a1 = r_a0 + 32;
    int r_b0 = wc * 64 + (lane & 31), r_b1 = r_b0 + 32;

    for (int k0 = 0; k0 < D_DIM; k0 += 64) {
        __syncthreads();  // previous-iter reads done (also orders sqa/sqb writes)
        #pragma unroll
        for (int it = 0; it < 4; ++it) {
            int row   = w * 32 + it * 8 + (lane >> 3);
            int chunk = ((lane & 7) ^ ((lane >> 3) & 7)) << 3;  // elems
            const unsigned short* srcA = Xb + (size_t)(rowA0 + row) * D_DIM + k0 + chunk;
            const unsigned short* srcB = Xb + (size_t)(rowB0 + row) * D_DIM + k0 + chunk;
            unsigned short* dA = As + (w * 32 + it * 8) * 64;
            unsigned short* dB = Bs + (w * 32 + it * 8) * 64;
            __builtin_amdgcn_global_load_lds(AS_GLOBAL(srcA), AS_LDS(dA), 16, 0, 0);
            __builtin_amdgcn_global_load_lds(AS_GLOBAL(srcB), AS_LDS(dB), 16, 0, 0);
        }
        __syncthreads();  // staged data visible (compiler drains vmcnt before barrier)

        #pragma unroll
        for (int kk = 0; kk < 4; ++kk) {
            int kb = kk * 32 + ((lane >> 5) << 4);  // byte offset of lane's 16B k-chunk
            short8v a0 = frag_read(As, r_a0, kb);
            short8v a1 = frag_read(As, r_a1, kb);
            short8v b0 = frag_read(Bs, r_b0, kb);
            short8v b1 = frag_read(Bs, r_b1, kb);
            acc[0][0] = __builtin_amdgcn_mfma_f32_32x32x16_bf16(a0, b0, acc[0][0], 0, 0, 0);
            acc[0][1] = __builtin_amdgcn_mfma_f32_32x32x16_bf16(a0, b1, acc[0][1], 0, 0, 0);
            acc[1][0] = __builtin_amdgcn_mfma_f32_32x32x16_bf16(a1, b0, acc[1][0], 0, 0, 0);
            acc[1][1] = __builtin_amdgcn_mfma_f32_32x32x16_bf16(a1, b1, acc[1][1], 0, 0, 0);
        }
    }

    // Epilogue: e = exp(-2 * max(sq_i + sq_j - 2*dot, 0)), reduce.
    // C layout (32x32): col = lane&31, row = (reg&3) + 8*(reg>>2) + 4*(lane>>5)
    float s = 0.0f;
    int col = lane & 31;
    int rhi = (lane >> 5) * 4;
    #pragma unroll
    for (int si = 0; si < 2; ++si)
        #pragma unroll
        for (int sj = 0; sj < 2; ++sj)
            #pragma unroll
            for (int reg = 0; reg < 16; ++reg) {
                int il = wr * 64 + si * 32 + (reg & 3) + 8 * (reg >> 2) + rhi;
                int jl = wc * 64 + sj * 32 + col;
                float d2 = fmaxf(sqa[il] + sqb[jl] - 2.0f * acc[si][sj][reg], 0.0f);
                s += __expf(-2.0f * d2);
            }
    if (ib != jb) s *= 2.0f;

    #pragma unroll
    for (int off = 32; off > 0; off >>= 1) s += __shfl_down(s, off, 64);
    if (lane == 0) red[w] = s;
    __syncthreads();
    if (t == 0)
        atomicAdd(&partials[64 + ((ib * 7 + jb * 13) & 63)], red[0]+red[1]+red[2]+red[3]);
}

// ---------------------------------------------------------------------------
__global__ void finalize_kernel(const float* __restrict__ partials,
                                float* __restrict__ out, int B_rows) {
    int t = threadIdx.x;  // 64 threads
    float al = partials[t];
    float un = partials[64 + t];
    #pragma unroll
    for (int off = 32; off > 0; off >>= 1) {
        al += __shfl_down(al, off, 64);
        un += __shfl_down(un, off, 64);
    }
    if (t == 0) {
        float n = (float)(2 * B_rows);
        out[0] = al / (float)B_rows + (un - n) / (n * (n - 1.0f));
    }
}

// ---------------------------------------------------------------------------
extern "C" void kernel_launch(void* const* d_in, const int* in_sizes, int n_in,
                              void* d_out, int out_size, void* d_ws, size_t ws_size,
                              hipStream_t stream) {
    const float* A  = (const float*)d_in[0];
    const float* Bm = (const float*)d_in[1];
    float* out = (float*)d_out;

    int B_rows = in_sizes[0] / D_DIM;   // 4096
    int n_tot  = 2 * B_rows;            // 8192

    // ws layout: Xb (bf16 n*256 = 4 MB) | SQ (f32 n) | partials (f32 128)
    unsigned short* Xb = (unsigned short*)d_ws;
    float* SQ       = (float*)(Xb + (size_t)n_tot * D_DIM);
    float* partials = SQ + n_tot;

    hipMemsetAsync(partials, 0, 128 * sizeof(float), stream);

    normalize_kernel<<<B_rows / 4, 256, 0, stream>>>(A, Bm, Xb, SQ, partials, B_rows);

    int nb = n_tot / 128;  // 64
    uniform_mfma_kernel<<<dim3(nb, nb), 256, 0, stream>>>(Xb, SQ, partials);

    finalize_kernel<<<1, 64, 0, stream>>>(partials, out, B_rows);
}